// Round 10
// baseline (1349.163 us; speedup 1.0000x reference)
//
#include <hip/hip_runtime.h>
#include <hip/hip_bf16.h>

#define USER_NUM 100000
#define N_NODES  150000
#define EMB      64
#define NNZ      6400000
#define MATF ((size_t)N_NODES * EMB)   // elems per matrix (9.6M)
#define UMATF ((size_t)USER_NUM * EMB) // user-slice elems (6.4M)
#define IMATF ((size_t)(N_NODES - USER_NUM) * EMB) // item-slice elems (3.2M)

#define RPB1   512                      // rows per coarse bucket (row>>9)
#define NB1    ((N_NODES + RPB1 - 1) / RPB1)   // 293
#define CHUNK1 4096                     // edges staged per block in P1
#define NCB    19                       // column blocks of 8192 (col>>13)
#define NCELL  (RPB1 * NCB)             // 9728 p2 LDS cells

// ---------------------------------------------------------------------------
// Threefry-2x32, 20 rounds (JAX-compatible; verified passing).
// ---------------------------------------------------------------------------
__host__ __device__ __forceinline__ void tf_block(unsigned k0, unsigned k1,
                                                  unsigned x0, unsigned x1,
                                                  unsigned& o0, unsigned& o1) {
    unsigned ks[3] = {k0, k1, k0 ^ k1 ^ 0x1BD11BDAu};
    unsigned X0 = x0 + ks[0];
    unsigned X1 = x1 + ks[1];
    const int R[2][4] = {{13, 15, 26, 6}, {17, 29, 16, 24}};
#pragma unroll
    for (int i = 0; i < 5; ++i) {
        const int* r = R[i & 1];
#pragma unroll
        for (int j = 0; j < 4; ++j) {
            X0 += X1;
            X1 = (X1 << r[j]) | (X1 >> (32 - r[j]));
            X1 ^= X0;
        }
        X0 += ks[(i + 1) % 3];
        X1 += ks[(i + 2) % 3] + (unsigned)(i + 1);
    }
    o0 = X0; o1 = X1;
}

__device__ __forceinline__ unsigned short f_to_bfu(float f) {
    __hip_bfloat16 b = __float2bfloat16(f);   // RNE
    return *(unsigned short*)&b;
}
__device__ __forceinline__ float bfu_to_f(unsigned short u) {
    return __uint_as_float((unsigned)u << 16);
}

// ---------------------------------------------------------------------------
// Bucket histogram, LDS-aggregated (<=293 global atomics per block).
// ---------------------------------------------------------------------------
#define BHIST_BLOCKS 2048
__global__ __launch_bounds__(256) void bhist_k(const int* __restrict__ rows,
                                               int* __restrict__ bb) {
    __shared__ int h[NB1];
    for (int i = threadIdx.x; i < NB1; i += 256) h[i] = 0;
    __syncthreads();
    const int stride = BHIST_BLOCKS * 256;
    for (int e = blockIdx.x * 256 + threadIdx.x; e < NNZ; e += stride)
        atomicAdd(&h[rows[e] >> 9], 1);
    __syncthreads();
    for (int i = threadIdx.x; i < NB1; i += 256)
        if (h[i]) atomicAdd(&bb[i], h[i]);
}

__global__ __launch_bounds__(512) void bscan_k(int* __restrict__ bb,
                                               int* __restrict__ bcur) {
    __shared__ int sh[512];
    int t = threadIdx.x;
    int v = (t < NB1) ? bb[t] : 0;
    sh[t] = v;
    __syncthreads();
    for (int off = 1; off < 512; off <<= 1) {
        int x = (t >= off) ? sh[t - off] : 0;
        __syncthreads();
        sh[t] += x;
        __syncthreads();
    }
    int ex = sh[t] - v;  // exclusive prefix
    if (t < NB1) { bb[t] = ex; bcur[t] = ex; }
    if (t == NB1 - 1) bb[NB1] = sh[t];   // sentinel = NNZ
}

// ---------------------------------------------------------------------------
// P1: LDS-staged coarse scatter (write-combined).
// ---------------------------------------------------------------------------
__global__ __launch_bounds__(256) void p1_k(const int* __restrict__ rows,
                                            const int* __restrict__ cols,
                                            const float* __restrict__ vals,
                                            int* __restrict__ bcur,
                                            int2* __restrict__ tmp) {
    __shared__ int2 stage[CHUNK1];               // 32 KB
    __shared__ unsigned short sb[CHUNK1];        // 8 KB: bucket id per slot
    __shared__ int hist[NB1], lbase[NB1], lcur[NB1], gbase[NB1];
    const int tid = threadIdx.x;
    const int c0 = blockIdx.x * CHUNK1;
    const int n = (c0 + CHUNK1 <= NNZ) ? CHUNK1 : (NNZ - c0);

    for (int b = tid; b < NB1; b += 256) hist[b] = 0;
    __syncthreads();

    int2 pay[CHUNK1 / 256];
    int  pb[CHUNK1 / 256];
#pragma unroll
    for (int k = 0; k < CHUNK1 / 256; ++k) {
        int i = tid + k * 256;
        if (i < n) {
            int e = c0 + i;
            int r = rows[e];
            int b = r >> 9;
            pay[k] = make_int2(cols[e] | ((r & 511) << 18),
                               __float_as_int(vals[e]));
            pb[k] = b;
            atomicAdd(&hist[b], 1);
        } else pb[k] = -1;
    }
    __syncthreads();

    if (tid == 0) {
        int run = 0;
        for (int b = 0; b < NB1; ++b) {
            lbase[b] = run;
            lcur[b] = run;
            run += hist[b];
        }
    }
    __syncthreads();
    for (int b = tid; b < NB1; b += 256)
        if (hist[b] > 0) gbase[b] = atomicAdd(&bcur[b], hist[b]);
    __syncthreads();

#pragma unroll
    for (int k = 0; k < CHUNK1 / 256; ++k) {
        if (pb[k] >= 0) {
            int pos = atomicAdd(&lcur[pb[k]], 1);
            stage[pos] = pay[k];
            sb[pos] = (unsigned short)pb[k];
        }
    }
    __syncthreads();

    for (int i = tid; i < n; i += 256) {
        int b = sb[i];
        tmp[gbase[b] + (i - lbase[b])] = stage[i];
    }
}

// ---------------------------------------------------------------------------
// P2: block per coarse bucket; (row, colblock)-sorted scatter + cur[] ends.
// ---------------------------------------------------------------------------
__global__ __launch_bounds__(256) void p2_k(const int* __restrict__ bb,
                                            const int2* __restrict__ tmp,
                                            int2* __restrict__ edges,
                                            int* __restrict__ cur) {
    __shared__ int lh[NCELL];     // 38.9 KB
    __shared__ int ps[256];
    int b = blockIdx.x;
    int tid = threadIdx.x;
    int base = bb[b];
    int cnt = bb[b + 1] - base;

    for (int i = tid; i < NCELL; i += 256) lh[i] = 0;
    __syncthreads();

    for (int i = tid; i < cnt; i += 256) {
        int x = tmp[base + i].x;
        int cell = ((x >> 18) & 511) * NCB + ((x & 0x3FFFF) >> 13);
        atomicAdd(&lh[cell], 1);
    }
    __syncthreads();

    const int PC = (NCELL + 255) / 256;   // 38
    int lo = tid * PC;
    int hi = lo + PC < NCELL ? lo + PC : NCELL;
    int s = 0;
    for (int i = lo; i < hi; ++i) s += lh[i];
    ps[tid] = s;
    __syncthreads();
    for (int off = 1; off < 256; off <<= 1) {
        int x = (tid >= off) ? ps[tid - off] : 0;
        __syncthreads();
        ps[tid] += x;
        __syncthreads();
    }
    int run = base + ps[tid] - s;
    for (int i = lo; i < hi; ++i) {
        int d = lh[i];
        lh[i] = run;
        run += d;
    }
    __syncthreads();

    for (int i = tid; i < cnt; i += 256) {
        int2 w = tmp[base + i];
        int cell = ((w.x >> 18) & 511) * NCB + ((w.x & 0x3FFFF) >> 13);
        int pos = atomicAdd(&lh[cell], 1);
        edges[pos] = make_int2(w.x & 0x3FFFF, w.y);
    }
    __syncthreads();

    int r0 = b * RPB1;
    for (int t = tid; t < RPB1; t += 256) {
        int r = r0 + t;
        if (r < N_NODES) cur[r] = lh[t * NCB + (NCB - 1)];
    }
}

// ---------------------------------------------------------------------------
// Pack layer-0 sources, exploiting the shared user slice:
//   pU[c*64+l]   = bf16(user)            for c <  USER_NUM   (2 B/lane)
//   pIE[c'*64+l] = bf16(item)            for item cols       (2 B/lane)
//   pIIT[c'*64+l]= bf16(img)|bf16(txt)<<16                   (4 B/lane)
// ---------------------------------------------------------------------------
__global__ __launch_bounds__(256) void pack0_k(
    const float* __restrict__ user, const float* __restrict__ item,
    const float* __restrict__ image, const float* __restrict__ text,
    unsigned short* __restrict__ pU, unsigned short* __restrict__ pIE,
    unsigned* __restrict__ pIIT) {
    size_t idx = (size_t)blockIdx.x * 256 + threadIdx.x;
    if (idx < UMATF) {
        pU[idx] = f_to_bfu(user[idx]);
    }
    if (idx < IMATF) {
        pIE[idx]  = f_to_bfu(item[idx]);
        pIIT[idx] = (unsigned)f_to_bfu(image[idx]) |
                    ((unsigned)f_to_bfu(text[idx]) << 16);
    }
}

// ---------------------------------------------------------------------------
// Fused SpMM + leaky-relu + threefry dropout + l2norm + output accumulation.
// One wave per row; lane == dim. FIRST specializes layer 0: user cols gather
// 2 B/lane (shared across E/I/T via su), item cols gather 6 B/lane.
// Streaming accesses (edges, out, write-backs) are nontemporal to keep L2
// free for the random gathers.
// ---------------------------------------------------------------------------
template <bool FIRST>
__global__ __launch_bounds__(256) void spmm_post(
    const int* __restrict__ cur, const int2* __restrict__ edges,
    const unsigned short* __restrict__ sE, const unsigned* __restrict__ sIT,
    const unsigned short* __restrict__ pU, const unsigned short* __restrict__ pIE,
    const unsigned* __restrict__ pIIT,
    unsigned short* __restrict__ dE, unsigned* __restrict__ dIT,
    const float* __restrict__ w, float* __restrict__ out,
    unsigned ki0, unsigned ki1, unsigned kt0, unsigned kt1, int writeBack) {
    int row = (int)((blockIdx.x * 256u + threadIdx.x) >> 6);
    int lane = threadIdx.x & 63;
    if (row >= N_NODES) return;
    int beg = __builtin_amdgcn_readfirstlane((row == 0) ? 0 : cur[row - 1]);
    int end = __builtin_amdgcn_readfirstlane(cur[row]);
    const long long* edges64 = (const long long*)edges;
    float ae = 0.f, ai = 0.f, at = 0.f, su = 0.f;
#pragma unroll 8
    for (int i = beg; i < end; ++i) {
        long long cvp = __builtin_nontemporal_load(edges64 + i);
        int c = (int)(unsigned)(cvp & 0xffffffffu);
        float v = __uint_as_float((unsigned)((unsigned long long)cvp >> 32));
        if (FIRST) {
            if (c < USER_NUM) {
                float u = bfu_to_f(pU[(size_t)c * EMB + lane]);
                su += v * u;
            } else {
                size_t cc = (size_t)(c - USER_NUM) * EMB + lane;
                float xe = bfu_to_f(pIE[cc]);
                unsigned it = pIIT[cc];
                ae += v * xe;
                ai += v * __uint_as_float(it << 16);
                at += v * __uint_as_float(it & 0xffff0000u);
            }
        } else {
            size_t cc = (size_t)c * EMB + lane;
            float xe = bfu_to_f(sE[cc]);
            unsigned it = sIT[cc];
            ae += v * xe;
            ai += v * __uint_as_float(it << 16);
            at += v * __uint_as_float(it & 0xffff0000u);
        }
    }
    if (FIRST) { ae += su; ai += su; at += su; }

    size_t idx = (size_t)row * EMB + lane;
    unsigned j = (unsigned)idx;

    float iv = ai >= 0.f ? ai : 0.01f * ai;      // leaky_relu
    float tv = at >= 0.f ? at : 0.01f * at;
    unsigned y0, y1;
    tf_block(ki0, ki1, 0u, j, y0, y1);
    iv = ((y0 ^ y1) >> 31) ? 0.f : iv * 2.f;     // dropout p=0.5, keep iff MSB==0
    tf_block(kt0, kt1, 0u, j, y0, y1);
    tv = ((y0 ^ y1) >> 31) ? 0.f : tv * 2.f;

    if (writeBack) {                              // next layer's SpMM inputs
        __builtin_nontemporal_store(f_to_bfu(ae), &dE[idx]);
        __builtin_nontemporal_store(
            (unsigned)f_to_bfu(iv) | ((unsigned)f_to_bfu(tv) << 16), &dIT[idx]);
    }

    // row-wise l2 norms across the 64 lanes (full f32 values)
    float si = iv * iv, st2 = tv * tv;
#pragma unroll
    for (int m = 1; m < 64; m <<= 1) {
        si  += __shfl_xor(si, m, 64);
        st2 += __shfl_xor(st2, m, 64);
    }
    float ni = iv / fmaxf(sqrtf(si), 1e-12f);
    float nt = tv / fmaxf(sqrtf(st2), 1e-12f);

    const float inv3 = 1.0f / 3.0f;
    float contrib = (row < USER_NUM) ? ae * inv3
                                     : (w[0] * ae + w[1] * ni + w[2] * nt) * inv3;
    if (FIRST) {
        __builtin_nontemporal_store(contrib, &out[idx]);   // overwrite, no memset
    } else {
        float o = __builtin_nontemporal_load(&out[idx]);
        __builtin_nontemporal_store(o + contrib, &out[idx]);
    }
}

// ---------------------------------------------------------------------------
extern "C" void kernel_launch(void* const* d_in, const int* in_sizes, int n_in,
                              void* d_out, int out_size, void* d_ws, size_t ws_size,
                              hipStream_t stream) {
    const float* user  = (const float*)d_in[0];
    const float* item  = (const float*)d_in[1];
    const float* image = (const float*)d_in[2];
    const float* text  = (const float*)d_in[3];
    const float* w     = (const float*)d_in[4];
    const float* vals  = (const float*)d_in[5];
    const int*   rows  = (const int*)d_in[6];
    const int*   cols  = (const int*)d_in[7];
    float* out = (float*)d_out;

    // workspace layout (~199 MB)
    int2* edges = (int2*)d_ws;                               // NNZ * 8B
    unsigned short* eA = (unsigned short*)(edges + NNZ);     // E ping (bf16)
    unsigned short* eB = eA + MATF;                          // E pong
    unsigned* itA = (unsigned*)(eB + MATF);                  // IT ping (2xbf16)
    unsigned* itB = itA + MATF;                              // IT pong
    unsigned short* pU  = (unsigned short*)(itB + MATF);     // user slice (bf16)
    unsigned short* pIE = pU + UMATF;                        // item E slice
    unsigned* pIIT = (unsigned*)(pIE + IMATF);               // item I|T slice
    int* cur  = (int*)(pIIT + IMATF);                        // N_NODES
    int* bb   = cur + N_NODES;                               // NB1 + 1
    int* bcur = bb + (NB1 + 2);                              // NB1
    // tmp bucket buffer aliased onto (eB, itA): dead before spmm layer 0/1
    // write them (stream-ordered after p2_k).
    int2* tmp = (int2*)eB;                                   // NNZ * 8B

    // ---- CSR build: bucket hist/scan + write-combined 2-pass sort ----
    hipMemsetAsync(bb, 0, (NB1 + 1) * sizeof(int), stream);
    bhist_k<<<BHIST_BLOCKS, 256, 0, stream>>>(rows, bb);
    bscan_k<<<1, 512, 0, stream>>>(bb, bcur);
    p1_k<<<(NNZ + CHUNK1 - 1) / CHUNK1, 256, 0, stream>>>(rows, cols, vals,
                                                          bcur, tmp);
    p2_k<<<NB1, 256, 0, stream>>>(bb, tmp, edges, cur);

    const int blocks = (int)((MATF + 255) / 256);  // 37500: one wave per row
    pack0_k<<<(int)((UMATF + 255) / 256), 256, 0, stream>>>(
        user, item, image, text, pU, pIE, pIIT);

    // layer 0: reads pU/pIE/pIIT, writes eA/itA
    // layer 1: reads eA/itA,      writes eB/itB
    // layer 2: reads eB/itB,      writes nothing
    for (int k = 0; k < 3; ++k) {
        unsigned f0, f1, a0, a1, b0, b1;
        tf_block(0u, 42u, 0u, (unsigned)k, f0, f1);
        tf_block(f0, f1, 0u, 0u, a0, a1);
        tf_block(f0, f1, 0u, 1u, b0, b1);
        if (k == 0) {
            spmm_post<true><<<blocks, 256, 0, stream>>>(
                cur, edges, nullptr, nullptr, pU, pIE, pIIT,
                eA, itA, w, out, a0, a1, b0, b1, 1);
        } else if (k == 1) {
            spmm_post<false><<<blocks, 256, 0, stream>>>(
                cur, edges, eA, itA, nullptr, nullptr, nullptr,
                eB, itB, w, out, a0, a1, b0, b1, 1);
        } else {
            spmm_post<false><<<blocks, 256, 0, stream>>>(
                cur, edges, eB, itB, nullptr, nullptr, nullptr,
                nullptr, nullptr, w, out, a0, a1, b0, b1, 0);
        }
    }
}

// Round 11
// 1338.542 us; speedup vs baseline: 1.0079x; 1.0079x over previous
//
#include <hip/hip_runtime.h>
#include <hip/hip_bf16.h>

#define USER_NUM 100000
#define N_NODES  150000
#define EMB      64
#define NNZ      6400000
#define MATF ((size_t)N_NODES * EMB)   // elems per matrix (9.6M)
#define UMATF ((size_t)USER_NUM * EMB) // user-slice elems (6.4M)
#define IMATF ((size_t)(N_NODES - USER_NUM) * EMB) // item-slice elems (3.2M)

#define RPB1   512                      // rows per coarse bucket (row>>9)
#define NB1    ((N_NODES + RPB1 - 1) / RPB1)   // 293
#define CHUNK1 4096                     // edges staged per block in P1
#define NCB    19                       // column blocks of 8192 (col>>13)
#define NCELL  (RPB1 * NCB)             // 9728 p2 LDS cells

// ---------------------------------------------------------------------------
// Threefry-2x32, 20 rounds (JAX-compatible; verified passing).
// ---------------------------------------------------------------------------
__host__ __device__ __forceinline__ void tf_block(unsigned k0, unsigned k1,
                                                  unsigned x0, unsigned x1,
                                                  unsigned& o0, unsigned& o1) {
    unsigned ks[3] = {k0, k1, k0 ^ k1 ^ 0x1BD11BDAu};
    unsigned X0 = x0 + ks[0];
    unsigned X1 = x1 + ks[1];
    const int R[2][4] = {{13, 15, 26, 6}, {17, 29, 16, 24}};
#pragma unroll
    for (int i = 0; i < 5; ++i) {
        const int* r = R[i & 1];
#pragma unroll
        for (int j = 0; j < 4; ++j) {
            X0 += X1;
            X1 = (X1 << r[j]) | (X1 >> (32 - r[j]));
            X1 ^= X0;
        }
        X0 += ks[(i + 1) % 3];
        X1 += ks[(i + 2) % 3] + (unsigned)(i + 1);
    }
    o0 = X0; o1 = X1;
}

__device__ __forceinline__ unsigned short f_to_bfu(float f) {
    __hip_bfloat16 b = __float2bfloat16(f);   // RNE
    return *(unsigned short*)&b;
}
__device__ __forceinline__ float bfu_to_f(unsigned short u) {
    return __uint_as_float((unsigned)u << 16);
}

// ---------------------------------------------------------------------------
// Bucket histogram, LDS-aggregated (<=293 global atomics per block).
// ---------------------------------------------------------------------------
#define BHIST_BLOCKS 2048
__global__ __launch_bounds__(256) void bhist_k(const int* __restrict__ rows,
                                               int* __restrict__ bb) {
    __shared__ int h[NB1];
    for (int i = threadIdx.x; i < NB1; i += 256) h[i] = 0;
    __syncthreads();
    const int stride = BHIST_BLOCKS * 256;
    for (int e = blockIdx.x * 256 + threadIdx.x; e < NNZ; e += stride)
        atomicAdd(&h[rows[e] >> 9], 1);
    __syncthreads();
    for (int i = threadIdx.x; i < NB1; i += 256)
        if (h[i]) atomicAdd(&bb[i], h[i]);
}

__global__ __launch_bounds__(512) void bscan_k(int* __restrict__ bb,
                                               int* __restrict__ bcur) {
    __shared__ int sh[512];
    int t = threadIdx.x;
    int v = (t < NB1) ? bb[t] : 0;
    sh[t] = v;
    __syncthreads();
    for (int off = 1; off < 512; off <<= 1) {
        int x = (t >= off) ? sh[t - off] : 0;
        __syncthreads();
        sh[t] += x;
        __syncthreads();
    }
    int ex = sh[t] - v;  // exclusive prefix
    if (t < NB1) { bb[t] = ex; bcur[t] = ex; }
    if (t == NB1 - 1) bb[NB1] = sh[t];   // sentinel = NNZ
}

// ---------------------------------------------------------------------------
// P1: LDS-staged coarse scatter (write-combined).
// ---------------------------------------------------------------------------
__global__ __launch_bounds__(256) void p1_k(const int* __restrict__ rows,
                                            const int* __restrict__ cols,
                                            const float* __restrict__ vals,
                                            int* __restrict__ bcur,
                                            int2* __restrict__ tmp) {
    __shared__ int2 stage[CHUNK1];               // 32 KB
    __shared__ unsigned short sb[CHUNK1];        // 8 KB: bucket id per slot
    __shared__ int hist[NB1], lbase[NB1], lcur[NB1], gbase[NB1];
    const int tid = threadIdx.x;
    const int c0 = blockIdx.x * CHUNK1;
    const int n = (c0 + CHUNK1 <= NNZ) ? CHUNK1 : (NNZ - c0);

    for (int b = tid; b < NB1; b += 256) hist[b] = 0;
    __syncthreads();

    int2 pay[CHUNK1 / 256];
    int  pb[CHUNK1 / 256];
#pragma unroll
    for (int k = 0; k < CHUNK1 / 256; ++k) {
        int i = tid + k * 256;
        if (i < n) {
            int e = c0 + i;
            int r = rows[e];
            int b = r >> 9;
            pay[k] = make_int2(cols[e] | ((r & 511) << 18),
                               __float_as_int(vals[e]));
            pb[k] = b;
            atomicAdd(&hist[b], 1);
        } else pb[k] = -1;
    }
    __syncthreads();

    if (tid == 0) {
        int run = 0;
        for (int b = 0; b < NB1; ++b) {
            lbase[b] = run;
            lcur[b] = run;
            run += hist[b];
        }
    }
    __syncthreads();
    for (int b = tid; b < NB1; b += 256)
        if (hist[b] > 0) gbase[b] = atomicAdd(&bcur[b], hist[b]);
    __syncthreads();

#pragma unroll
    for (int k = 0; k < CHUNK1 / 256; ++k) {
        if (pb[k] >= 0) {
            int pos = atomicAdd(&lcur[pb[k]], 1);
            stage[pos] = pay[k];
            sb[pos] = (unsigned short)pb[k];
        }
    }
    __syncthreads();

    for (int i = tid; i < n; i += 256) {
        int b = sb[i];
        tmp[gbase[b] + (i - lbase[b])] = stage[i];
    }
}

// ---------------------------------------------------------------------------
// P2: block per coarse bucket; (row, colblock)-sorted scatter + cur[] ends.
// ---------------------------------------------------------------------------
__global__ __launch_bounds__(256) void p2_k(const int* __restrict__ bb,
                                            const int2* __restrict__ tmp,
                                            int2* __restrict__ edges,
                                            int* __restrict__ cur) {
    __shared__ int lh[NCELL];     // 38.9 KB
    __shared__ int ps[256];
    int b = blockIdx.x;
    int tid = threadIdx.x;
    int base = bb[b];
    int cnt = bb[b + 1] - base;

    for (int i = tid; i < NCELL; i += 256) lh[i] = 0;
    __syncthreads();

    for (int i = tid; i < cnt; i += 256) {
        int x = tmp[base + i].x;
        int cell = ((x >> 18) & 511) * NCB + ((x & 0x3FFFF) >> 13);
        atomicAdd(&lh[cell], 1);
    }
    __syncthreads();

    const int PC = (NCELL + 255) / 256;   // 38
    int lo = tid * PC;
    int hi = lo + PC < NCELL ? lo + PC : NCELL;
    int s = 0;
    for (int i = lo; i < hi; ++i) s += lh[i];
    ps[tid] = s;
    __syncthreads();
    for (int off = 1; off < 256; off <<= 1) {
        int x = (tid >= off) ? ps[tid - off] : 0;
        __syncthreads();
        ps[tid] += x;
        __syncthreads();
    }
    int run = base + ps[tid] - s;
    for (int i = lo; i < hi; ++i) {
        int d = lh[i];
        lh[i] = run;
        run += d;
    }
    __syncthreads();

    for (int i = tid; i < cnt; i += 256) {
        int2 w = tmp[base + i];
        int cell = ((w.x >> 18) & 511) * NCB + ((w.x & 0x3FFFF) >> 13);
        int pos = atomicAdd(&lh[cell], 1);
        edges[pos] = make_int2(w.x & 0x3FFFF, w.y);
    }
    __syncthreads();

    int r0 = b * RPB1;
    for (int t = tid; t < RPB1; t += 256) {
        int r = r0 + t;
        if (r < N_NODES) cur[r] = lh[t * NCB + (NCB - 1)];
    }
}

// ---------------------------------------------------------------------------
// Pack layer-0 sources, exploiting the shared user slice:
//   pU[c*64+l]   = bf16(user)            for c <  USER_NUM   (2 B/lane)
//   pIE[c'*64+l] = bf16(item)            for item cols       (2 B/lane)
//   pIIT[c'*64+l]= bf16(img)|bf16(txt)<<16                   (4 B/lane)
// ---------------------------------------------------------------------------
__global__ __launch_bounds__(256) void pack0_k(
    const float* __restrict__ user, const float* __restrict__ item,
    const float* __restrict__ image, const float* __restrict__ text,
    unsigned short* __restrict__ pU, unsigned short* __restrict__ pIE,
    unsigned* __restrict__ pIIT) {
    size_t idx = (size_t)blockIdx.x * 256 + threadIdx.x;
    if (idx < UMATF) {
        pU[idx] = f_to_bfu(user[idx]);
    }
    if (idx < IMATF) {
        pIE[idx]  = f_to_bfu(item[idx]);
        pIIT[idx] = (unsigned)f_to_bfu(image[idx]) |
                    ((unsigned)f_to_bfu(text[idx]) << 16);
    }
}

// ---------------------------------------------------------------------------
// Fused SpMM + leaky-relu + threefry dropout + l2norm + output accumulation.
// One wave per row; lane == dim. FIRST specializes layer 0: user cols gather
// 2 B/lane (shared across E/I/T via su), item cols gather 6 B/lane.
// Plain (cached) loads everywhere: the wave-uniform edge stream must stay in
// L1 — nontemporal on it put L2 latency on the gather-address chain (round 10:
// dur 338->401 us despite halved FETCH).
// ---------------------------------------------------------------------------
template <bool FIRST>
__global__ __launch_bounds__(256) void spmm_post(
    const int* __restrict__ cur, const int2* __restrict__ edges,
    const unsigned short* __restrict__ sE, const unsigned* __restrict__ sIT,
    const unsigned short* __restrict__ pU, const unsigned short* __restrict__ pIE,
    const unsigned* __restrict__ pIIT,
    unsigned short* __restrict__ dE, unsigned* __restrict__ dIT,
    const float* __restrict__ w, float* __restrict__ out,
    unsigned ki0, unsigned ki1, unsigned kt0, unsigned kt1, int writeBack) {
    int row = (int)((blockIdx.x * 256u + threadIdx.x) >> 6);
    int lane = threadIdx.x & 63;
    if (row >= N_NODES) return;
    int beg = __builtin_amdgcn_readfirstlane((row == 0) ? 0 : cur[row - 1]);
    int end = __builtin_amdgcn_readfirstlane(cur[row]);
    float ae = 0.f, ai = 0.f, at = 0.f, su = 0.f;
#pragma unroll 8
    for (int i = beg; i < end; ++i) {
        int2 cv = edges[i];            // wave-uniform 8B load, L1-cached
        int c = cv.x;
        float v = __int_as_float(cv.y);
        if (FIRST) {
            if (c < USER_NUM) {
                float u = bfu_to_f(pU[(size_t)c * EMB + lane]);
                su += v * u;
            } else {
                size_t cc = (size_t)(c - USER_NUM) * EMB + lane;
                float xe = bfu_to_f(pIE[cc]);
                unsigned it = pIIT[cc];
                ae += v * xe;
                ai += v * __uint_as_float(it << 16);
                at += v * __uint_as_float(it & 0xffff0000u);
            }
        } else {
            size_t cc = (size_t)c * EMB + lane;
            float xe = bfu_to_f(sE[cc]);
            unsigned it = sIT[cc];
            ae += v * xe;
            ai += v * __uint_as_float(it << 16);
            at += v * __uint_as_float(it & 0xffff0000u);
        }
    }
    if (FIRST) { ae += su; ai += su; at += su; }

    size_t idx = (size_t)row * EMB + lane;
    unsigned j = (unsigned)idx;

    float iv = ai >= 0.f ? ai : 0.01f * ai;      // leaky_relu
    float tv = at >= 0.f ? at : 0.01f * at;
    unsigned y0, y1;
    tf_block(ki0, ki1, 0u, j, y0, y1);
    iv = ((y0 ^ y1) >> 31) ? 0.f : iv * 2.f;     // dropout p=0.5, keep iff MSB==0
    tf_block(kt0, kt1, 0u, j, y0, y1);
    tv = ((y0 ^ y1) >> 31) ? 0.f : tv * 2.f;

    if (writeBack) {                              // next layer's SpMM inputs
        dE[idx]  = f_to_bfu(ae);
        dIT[idx] = (unsigned)f_to_bfu(iv) | ((unsigned)f_to_bfu(tv) << 16);
    }

    // row-wise l2 norms across the 64 lanes (full f32 values)
    float si = iv * iv, st2 = tv * tv;
#pragma unroll
    for (int m = 1; m < 64; m <<= 1) {
        si  += __shfl_xor(si, m, 64);
        st2 += __shfl_xor(st2, m, 64);
    }
    float ni = iv / fmaxf(sqrtf(si), 1e-12f);
    float nt = tv / fmaxf(sqrtf(st2), 1e-12f);

    const float inv3 = 1.0f / 3.0f;
    float contrib = (row < USER_NUM) ? ae * inv3
                                     : (w[0] * ae + w[1] * ni + w[2] * nt) * inv3;
    if (FIRST) out[idx] = contrib;               // overwrite, no memset
    else       out[idx] += contrib;
}

// ---------------------------------------------------------------------------
extern "C" void kernel_launch(void* const* d_in, const int* in_sizes, int n_in,
                              void* d_out, int out_size, void* d_ws, size_t ws_size,
                              hipStream_t stream) {
    const float* user  = (const float*)d_in[0];
    const float* item  = (const float*)d_in[1];
    const float* image = (const float*)d_in[2];
    const float* text  = (const float*)d_in[3];
    const float* w     = (const float*)d_in[4];
    const float* vals  = (const float*)d_in[5];
    const int*   rows  = (const int*)d_in[6];
    const int*   cols  = (const int*)d_in[7];
    float* out = (float*)d_out;

    // workspace layout (~199 MB)
    int2* edges = (int2*)d_ws;                               // NNZ * 8B
    unsigned short* eA = (unsigned short*)(edges + NNZ);     // E ping (bf16)
    unsigned short* eB = eA + MATF;                          // E pong
    unsigned* itA = (unsigned*)(eB + MATF);                  // IT ping (2xbf16)
    unsigned* itB = itA + MATF;                              // IT pong
    unsigned short* pU  = (unsigned short*)(itB + MATF);     // user slice (bf16)
    unsigned short* pIE = pU + UMATF;                        // item E slice
    unsigned* pIIT = (unsigned*)(pIE + IMATF);               // item I|T slice
    int* cur  = (int*)(pIIT + IMATF);                        // N_NODES
    int* bb   = cur + N_NODES;                               // NB1 + 1
    int* bcur = bb + (NB1 + 2);                              // NB1
    // tmp bucket buffer aliased onto (eB, itA): dead before spmm layer 0/1
    // write them (stream-ordered after p2_k).
    int2* tmp = (int2*)eB;                                   // NNZ * 8B

    // ---- CSR build: bucket hist/scan + write-combined 2-pass sort ----
    hipMemsetAsync(bb, 0, (NB1 + 1) * sizeof(int), stream);
    bhist_k<<<BHIST_BLOCKS, 256, 0, stream>>>(rows, bb);
    bscan_k<<<1, 512, 0, stream>>>(bb, bcur);
    p1_k<<<(NNZ + CHUNK1 - 1) / CHUNK1, 256, 0, stream>>>(rows, cols, vals,
                                                          bcur, tmp);
    p2_k<<<NB1, 256, 0, stream>>>(bb, tmp, edges, cur);

    const int blocks = (int)((MATF + 255) / 256);  // 37500: one wave per row
    pack0_k<<<(int)((UMATF + 255) / 256), 256, 0, stream>>>(
        user, item, image, text, pU, pIE, pIIT);

    // layer 0: reads pU/pIE/pIIT, writes eA/itA
    // layer 1: reads eA/itA,      writes eB/itB
    // layer 2: reads eB/itB,      writes nothing
    for (int k = 0; k < 3; ++k) {
        unsigned f0, f1, a0, a1, b0, b1;
        tf_block(0u, 42u, 0u, (unsigned)k, f0, f1);
        tf_block(f0, f1, 0u, 0u, a0, a1);
        tf_block(f0, f1, 0u, 1u, b0, b1);
        if (k == 0) {
            spmm_post<true><<<blocks, 256, 0, stream>>>(
                cur, edges, nullptr, nullptr, pU, pIE, pIIT,
                eA, itA, w, out, a0, a1, b0, b1, 1);
        } else if (k == 1) {
            spmm_post<false><<<blocks, 256, 0, stream>>>(
                cur, edges, eA, itA, nullptr, nullptr, nullptr,
                eB, itB, w, out, a0, a1, b0, b1, 1);
        } else {
            spmm_post<false><<<blocks, 256, 0, stream>>>(
                cur, edges, eB, itB, nullptr, nullptr, nullptr,
                nullptr, nullptr, w, out, a0, a1, b0, b1, 0);
        }
    }
}

// Round 12
// 1336.423 us; speedup vs baseline: 1.0095x; 1.0016x over previous
//
#include <hip/hip_runtime.h>
#include <hip/hip_bf16.h>

#define USER_NUM 100000
#define N_NODES  150000
#define EMB      64
#define NNZ      6400000
#define MATF ((size_t)N_NODES * EMB)   // elems per matrix (9.6M)
#define UMATF ((size_t)USER_NUM * EMB) // user-slice elems (6.4M)
#define IMATF ((size_t)(N_NODES - USER_NUM) * EMB) // item-slice elems (3.2M)

#define RPB1   512                      // rows per coarse bucket (row>>9)
#define NB1    ((N_NODES + RPB1 - 1) / RPB1)   // 293
#define CHUNK1 4096                     // edges staged per block in P1
#define NCB    19                       // column blocks of 8192 (col>>13)
#define NCELL  (RPB1 * NCB)             // 9728 p2 LDS cells

// ---------------------------------------------------------------------------
// Threefry-2x32, 20 rounds (JAX-compatible; verified passing).
// ---------------------------------------------------------------------------
__host__ __device__ __forceinline__ void tf_block(unsigned k0, unsigned k1,
                                                  unsigned x0, unsigned x1,
                                                  unsigned& o0, unsigned& o1) {
    unsigned ks[3] = {k0, k1, k0 ^ k1 ^ 0x1BD11BDAu};
    unsigned X0 = x0 + ks[0];
    unsigned X1 = x1 + ks[1];
    const int R[2][4] = {{13, 15, 26, 6}, {17, 29, 16, 24}};
#pragma unroll
    for (int i = 0; i < 5; ++i) {
        const int* r = R[i & 1];
#pragma unroll
        for (int j = 0; j < 4; ++j) {
            X0 += X1;
            X1 = (X1 << r[j]) | (X1 >> (32 - r[j]));
            X1 ^= X0;
        }
        X0 += ks[(i + 1) % 3];
        X1 += ks[(i + 2) % 3] + (unsigned)(i + 1);
    }
    o0 = X0; o1 = X1;
}

__device__ __forceinline__ unsigned short f_to_bfu(float f) {
    __hip_bfloat16 b = __float2bfloat16(f);   // RNE
    return *(unsigned short*)&b;
}
__device__ __forceinline__ float bfu_to_f(unsigned short u) {
    return __uint_as_float((unsigned)u << 16);
}

// ---------------------------------------------------------------------------
// Bucket histogram, LDS-aggregated (<=293 global atomics per block).
// ---------------------------------------------------------------------------
#define BHIST_BLOCKS 2048
__global__ __launch_bounds__(256) void bhist_k(const int* __restrict__ rows,
                                               int* __restrict__ bb) {
    __shared__ int h[NB1];
    for (int i = threadIdx.x; i < NB1; i += 256) h[i] = 0;
    __syncthreads();
    const int stride = BHIST_BLOCKS * 256;
    for (int e = blockIdx.x * 256 + threadIdx.x; e < NNZ; e += stride)
        atomicAdd(&h[rows[e] >> 9], 1);
    __syncthreads();
    for (int i = threadIdx.x; i < NB1; i += 256)
        if (h[i]) atomicAdd(&bb[i], h[i]);
}

__global__ __launch_bounds__(512) void bscan_k(int* __restrict__ bb,
                                               int* __restrict__ bcur) {
    __shared__ int sh[512];
    int t = threadIdx.x;
    int v = (t < NB1) ? bb[t] : 0;
    sh[t] = v;
    __syncthreads();
    for (int off = 1; off < 512; off <<= 1) {
        int x = (t >= off) ? sh[t - off] : 0;
        __syncthreads();
        sh[t] += x;
        __syncthreads();
    }
    int ex = sh[t] - v;  // exclusive prefix
    if (t < NB1) { bb[t] = ex; bcur[t] = ex; }
    if (t == NB1 - 1) bb[NB1] = sh[t];   // sentinel = NNZ
}

// ---------------------------------------------------------------------------
// P1: LDS-staged coarse scatter (write-combined).
// ---------------------------------------------------------------------------
__global__ __launch_bounds__(256) void p1_k(const int* __restrict__ rows,
                                            const int* __restrict__ cols,
                                            const float* __restrict__ vals,
                                            int* __restrict__ bcur,
                                            int2* __restrict__ tmp) {
    __shared__ int2 stage[CHUNK1];               // 32 KB
    __shared__ unsigned short sb[CHUNK1];        // 8 KB: bucket id per slot
    __shared__ int hist[NB1], lbase[NB1], lcur[NB1], gbase[NB1];
    const int tid = threadIdx.x;
    const int c0 = blockIdx.x * CHUNK1;
    const int n = (c0 + CHUNK1 <= NNZ) ? CHUNK1 : (NNZ - c0);

    for (int b = tid; b < NB1; b += 256) hist[b] = 0;
    __syncthreads();

    int2 pay[CHUNK1 / 256];
    int  pb[CHUNK1 / 256];
#pragma unroll
    for (int k = 0; k < CHUNK1 / 256; ++k) {
        int i = tid + k * 256;
        if (i < n) {
            int e = c0 + i;
            int r = rows[e];
            int b = r >> 9;
            pay[k] = make_int2(cols[e] | ((r & 511) << 18),
                               __float_as_int(vals[e]));
            pb[k] = b;
            atomicAdd(&hist[b], 1);
        } else pb[k] = -1;
    }
    __syncthreads();

    if (tid == 0) {
        int run = 0;
        for (int b = 0; b < NB1; ++b) {
            lbase[b] = run;
            lcur[b] = run;
            run += hist[b];
        }
    }
    __syncthreads();
    for (int b = tid; b < NB1; b += 256)
        if (hist[b] > 0) gbase[b] = atomicAdd(&bcur[b], hist[b]);
    __syncthreads();

#pragma unroll
    for (int k = 0; k < CHUNK1 / 256; ++k) {
        if (pb[k] >= 0) {
            int pos = atomicAdd(&lcur[pb[k]], 1);
            stage[pos] = pay[k];
            sb[pos] = (unsigned short)pb[k];
        }
    }
    __syncthreads();

    for (int i = tid; i < n; i += 256) {
        int b = sb[i];
        tmp[gbase[b] + (i - lbase[b])] = stage[i];
    }
}

// ---------------------------------------------------------------------------
// P2: block per coarse bucket; (row, colblock)-sorted scatter + cur[] ends.
// ---------------------------------------------------------------------------
__global__ __launch_bounds__(256) void p2_k(const int* __restrict__ bb,
                                            const int2* __restrict__ tmp,
                                            int2* __restrict__ edges,
                                            int* __restrict__ cur) {
    __shared__ int lh[NCELL];     // 38.9 KB
    __shared__ int ps[256];
    int b = blockIdx.x;
    int tid = threadIdx.x;
    int base = bb[b];
    int cnt = bb[b + 1] - base;

    for (int i = tid; i < NCELL; i += 256) lh[i] = 0;
    __syncthreads();

    for (int i = tid; i < cnt; i += 256) {
        int x = tmp[base + i].x;
        int cell = ((x >> 18) & 511) * NCB + ((x & 0x3FFFF) >> 13);
        atomicAdd(&lh[cell], 1);
    }
    __syncthreads();

    const int PC = (NCELL + 255) / 256;   // 38
    int lo = tid * PC;
    int hi = lo + PC < NCELL ? lo + PC : NCELL;
    int s = 0;
    for (int i = lo; i < hi; ++i) s += lh[i];
    ps[tid] = s;
    __syncthreads();
    for (int off = 1; off < 256; off <<= 1) {
        int x = (tid >= off) ? ps[tid - off] : 0;
        __syncthreads();
        ps[tid] += x;
        __syncthreads();
    }
    int run = base + ps[tid] - s;
    for (int i = lo; i < hi; ++i) {
        int d = lh[i];
        lh[i] = run;
        run += d;
    }
    __syncthreads();

    for (int i = tid; i < cnt; i += 256) {
        int2 w = tmp[base + i];
        int cell = ((w.x >> 18) & 511) * NCB + ((w.x & 0x3FFFF) >> 13);
        int pos = atomicAdd(&lh[cell], 1);
        edges[pos] = make_int2(w.x & 0x3FFFF, w.y);
    }
    __syncthreads();

    int r0 = b * RPB1;
    for (int t = tid; t < RPB1; t += 256) {
        int r = r0 + t;
        if (r < N_NODES) cur[r] = lh[t * NCB + (NCB - 1)];
    }
}

// ---------------------------------------------------------------------------
// Pack layer-0 sources, exploiting the shared user slice.
// ---------------------------------------------------------------------------
__global__ __launch_bounds__(256) void pack0_k(
    const float* __restrict__ user, const float* __restrict__ item,
    const float* __restrict__ image, const float* __restrict__ text,
    unsigned short* __restrict__ pU, unsigned short* __restrict__ pIE,
    unsigned* __restrict__ pIIT) {
    size_t idx = (size_t)blockIdx.x * 256 + threadIdx.x;
    if (idx < UMATF) {
        pU[idx] = f_to_bfu(user[idx]);
    }
    if (idx < IMATF) {
        pIE[idx]  = f_to_bfu(item[idx]);
        pIIT[idx] = (unsigned)f_to_bfu(image[idx]) |
                    ((unsigned)f_to_bfu(text[idx]) << 16);
    }
}

// ---------------------------------------------------------------------------
// Shared epilogue: leaky-relu + dropout + optional write-back + l2norm + out.
// ---------------------------------------------------------------------------
__device__ __forceinline__ void epilogue(
    int row, int lane, float ae, float ai, float at,
    unsigned short* dE, unsigned* dIT, const float* w, float* out,
    unsigned ki0, unsigned ki1, unsigned kt0, unsigned kt1,
    int writeBack, bool first) {
    size_t idx = (size_t)row * EMB + lane;
    unsigned j = (unsigned)idx;

    float iv = ai >= 0.f ? ai : 0.01f * ai;      // leaky_relu
    float tv = at >= 0.f ? at : 0.01f * at;
    unsigned y0, y1;
    tf_block(ki0, ki1, 0u, j, y0, y1);
    iv = ((y0 ^ y1) >> 31) ? 0.f : iv * 2.f;     // dropout p=0.5, keep iff MSB==0
    tf_block(kt0, kt1, 0u, j, y0, y1);
    tv = ((y0 ^ y1) >> 31) ? 0.f : tv * 2.f;

    if (writeBack) {                              // next layer's SpMM inputs
        dE[idx]  = f_to_bfu(ae);
        dIT[idx] = (unsigned)f_to_bfu(iv) | ((unsigned)f_to_bfu(tv) << 16);
    }

    float si = iv * iv, st2 = tv * tv;
#pragma unroll
    for (int m = 1; m < 64; m <<= 1) {
        si  += __shfl_xor(si, m, 64);
        st2 += __shfl_xor(st2, m, 64);
    }
    float ni = iv / fmaxf(sqrtf(si), 1e-12f);
    float nt = tv / fmaxf(sqrtf(st2), 1e-12f);

    const float inv3 = 1.0f / 3.0f;
    float contrib = (row < USER_NUM) ? ae * inv3
                                     : (w[0] * ae + w[1] * ni + w[2] * nt) * inv3;
    if (first) out[idx] = contrib;
    else       out[idx] += contrib;
}

// ---------------------------------------------------------------------------
// Layer 0 SpMM: user cols 2 B/lane shared gather, item cols 6 B/lane.
// ---------------------------------------------------------------------------
__global__ __launch_bounds__(256) void spmm_l0(
    const int* __restrict__ cur, const int2* __restrict__ edges,
    const unsigned short* __restrict__ pU, const unsigned short* __restrict__ pIE,
    const unsigned* __restrict__ pIIT,
    unsigned short* __restrict__ dE, unsigned* __restrict__ dIT,
    const float* __restrict__ w, float* __restrict__ out,
    unsigned ki0, unsigned ki1, unsigned kt0, unsigned kt1) {
    int row = (int)((blockIdx.x * 256u + threadIdx.x) >> 6);
    int lane = threadIdx.x & 63;
    if (row >= N_NODES) return;
    int beg = __builtin_amdgcn_readfirstlane((row == 0) ? 0 : cur[row - 1]);
    int end = __builtin_amdgcn_readfirstlane(cur[row]);
    float ae = 0.f, ai = 0.f, at = 0.f, su = 0.f;
#pragma unroll 8
    for (int i = beg; i < end; ++i) {
        int2 cv = edges[i];
        int c = cv.x;
        float v = __int_as_float(cv.y);
        if (c < USER_NUM) {
            su += v * bfu_to_f(pU[(size_t)c * EMB + lane]);
        } else {
            size_t cc = (size_t)(c - USER_NUM) * EMB + lane;
            float xe = bfu_to_f(pIE[cc]);
            unsigned it = pIIT[cc];
            ae += v * xe;
            ai += v * __uint_as_float(it << 16);
            at += v * __uint_as_float(it & 0xffff0000u);
        }
    }
    ae += su; ai += su; at += su;
    epilogue(row, lane, ae, ai, at, dE, dIT, w, out,
             ki0, ki1, kt0, kt1, 1, true);
}

// ---------------------------------------------------------------------------
// Layers 1-2 SpMM: manual 4-edge batching — all 8 gathers issued before any
// accumulate, forcing the compiler to keep >=8 loads in flight (round 11
// regression: compiler allocated 8 VGPRs -> MLP ~1 -> 402 us vs 338).
// ---------------------------------------------------------------------------
__global__ __launch_bounds__(256) void spmm_l12(
    const int* __restrict__ cur, const int2* __restrict__ edges,
    const unsigned short* __restrict__ sE, const unsigned* __restrict__ sIT,
    unsigned short* __restrict__ dE, unsigned* __restrict__ dIT,
    const float* __restrict__ w, float* __restrict__ out,
    unsigned ki0, unsigned ki1, unsigned kt0, unsigned kt1, int writeBack) {
    int row = (int)((blockIdx.x * 256u + threadIdx.x) >> 6);
    int lane = threadIdx.x & 63;
    if (row >= N_NODES) return;
    int beg = __builtin_amdgcn_readfirstlane((row == 0) ? 0 : cur[row - 1]);
    int end = __builtin_amdgcn_readfirstlane(cur[row]);
    float ae = 0.f, ai = 0.f, at = 0.f;

    int i = beg;
    for (; i + 4 <= end; i += 4) {
        int2 c0 = edges[i];
        int2 c1 = edges[i + 1];
        int2 c2 = edges[i + 2];
        int2 c3 = edges[i + 3];
        size_t a0 = (size_t)c0.x * EMB + lane;
        size_t a1 = (size_t)c1.x * EMB + lane;
        size_t a2 = (size_t)c2.x * EMB + lane;
        size_t a3 = (size_t)c3.x * EMB + lane;
        // issue all 8 gathers (independent -> scheduler hoists above uses)
        unsigned short e0 = sE[a0];
        unsigned short e1 = sE[a1];
        unsigned short e2 = sE[a2];
        unsigned short e3 = sE[a3];
        unsigned t0 = sIT[a0];
        unsigned t1 = sIT[a1];
        unsigned t2 = sIT[a2];
        unsigned t3 = sIT[a3];
        float v0 = __int_as_float(c0.y);
        float v1 = __int_as_float(c1.y);
        float v2 = __int_as_float(c2.y);
        float v3 = __int_as_float(c3.y);
        // same per-edge accumulation order as the scalar loop
        ae += v0 * bfu_to_f(e0);
        ai += v0 * __uint_as_float(t0 << 16);
        at += v0 * __uint_as_float(t0 & 0xffff0000u);
        ae += v1 * bfu_to_f(e1);
        ai += v1 * __uint_as_float(t1 << 16);
        at += v1 * __uint_as_float(t1 & 0xffff0000u);
        ae += v2 * bfu_to_f(e2);
        ai += v2 * __uint_as_float(t2 << 16);
        at += v2 * __uint_as_float(t2 & 0xffff0000u);
        ae += v3 * bfu_to_f(e3);
        ai += v3 * __uint_as_float(t3 << 16);
        at += v3 * __uint_as_float(t3 & 0xffff0000u);
    }
    for (; i < end; ++i) {
        int2 cv = edges[i];
        size_t cc = (size_t)cv.x * EMB + lane;
        float v = __int_as_float(cv.y);
        unsigned short xe = sE[cc];
        unsigned it = sIT[cc];
        ae += v * bfu_to_f(xe);
        ai += v * __uint_as_float(it << 16);
        at += v * __uint_as_float(it & 0xffff0000u);
    }
    epilogue(row, lane, ae, ai, at, dE, dIT, w, out,
             ki0, ki1, kt0, kt1, writeBack, false);
}

// ---------------------------------------------------------------------------
extern "C" void kernel_launch(void* const* d_in, const int* in_sizes, int n_in,
                              void* d_out, int out_size, void* d_ws, size_t ws_size,
                              hipStream_t stream) {
    const float* user  = (const float*)d_in[0];
    const float* item  = (const float*)d_in[1];
    const float* image = (const float*)d_in[2];
    const float* text  = (const float*)d_in[3];
    const float* w     = (const float*)d_in[4];
    const float* vals  = (const float*)d_in[5];
    const int*   rows  = (const int*)d_in[6];
    const int*   cols  = (const int*)d_in[7];
    float* out = (float*)d_out;

    // workspace layout (~199 MB)
    int2* edges = (int2*)d_ws;                               // NNZ * 8B
    unsigned short* eA = (unsigned short*)(edges + NNZ);     // E ping (bf16)
    unsigned short* eB = eA + MATF;                          // E pong
    unsigned* itA = (unsigned*)(eB + MATF);                  // IT ping (2xbf16)
    unsigned* itB = itA + MATF;                              // IT pong
    unsigned short* pU  = (unsigned short*)(itB + MATF);     // user slice (bf16)
    unsigned short* pIE = pU + UMATF;                        // item E slice
    unsigned* pIIT = (unsigned*)(pIE + IMATF);               // item I|T slice
    int* cur  = (int*)(pIIT + IMATF);                        // N_NODES
    int* bb   = cur + N_NODES;                               // NB1 + 1
    int* bcur = bb + (NB1 + 2);                              // NB1
    // tmp bucket buffer aliased onto (eB, itA): dead after p2_k completes.
    int2* tmp = (int2*)eB;                                   // NNZ * 8B

    // ---- CSR build: bucket hist/scan + write-combined 2-pass sort ----
    hipMemsetAsync(bb, 0, (NB1 + 1) * sizeof(int), stream);
    bhist_k<<<BHIST_BLOCKS, 256, 0, stream>>>(rows, bb);
    bscan_k<<<1, 512, 0, stream>>>(bb, bcur);
    p1_k<<<(NNZ + CHUNK1 - 1) / CHUNK1, 256, 0, stream>>>(rows, cols, vals,
                                                          bcur, tmp);
    p2_k<<<NB1, 256, 0, stream>>>(bb, tmp, edges, cur);

    const int blocks = (int)((MATF + 255) / 256);  // 37500: one wave per row
    pack0_k<<<(int)((UMATF + 255) / 256), 256, 0, stream>>>(
        user, item, image, text, pU, pIE, pIIT);

    // layer keys
    unsigned a0[3], a1[3], b0[3], b1[3];
    for (int k = 0; k < 3; ++k) {
        unsigned f0, f1;
        tf_block(0u, 42u, 0u, (unsigned)k, f0, f1);
        tf_block(f0, f1, 0u, 0u, a0[k], a1[k]);
        tf_block(f0, f1, 0u, 1u, b0[k], b1[k]);
    }

    // layer 0: reads pU/pIE/pIIT, writes eA/itA
    spmm_l0<<<blocks, 256, 0, stream>>>(
        cur, edges, pU, pIE, pIIT, eA, itA, w, out, a0[0], a1[0], b0[0], b1[0]);
    // layer 1: reads eA/itA, writes eB/itB
    spmm_l12<<<blocks, 256, 0, stream>>>(
        cur, edges, eA, itA, eB, itB, w, out, a0[1], a1[1], b0[1], b1[1], 1);
    // layer 2: reads eB/itB, writes nothing
    spmm_l12<<<blocks, 256, 0, stream>>>(
        cur, edges, eB, itB, nullptr, nullptr, w, out, a0[2], a1[2], b0[2], b1[2], 0);
}

// Round 14
// 1172.852 us; speedup vs baseline: 1.1503x; 1.1395x over previous
//
#include <hip/hip_runtime.h>
#include <hip/hip_bf16.h>

#define USER_NUM 100000
#define N_NODES  150000
#define EMB      64
#define NNZ      6400000
#define MATF ((size_t)N_NODES * EMB)   // elems per matrix (9.6M)
#define UMATF ((size_t)USER_NUM * EMB) // user-slice elems (6.4M)
#define IMATF ((size_t)(N_NODES - USER_NUM) * EMB) // item-slice elems (3.2M)

#define RPB1   512                      // rows per coarse bucket (row>>9)
#define NB1    ((N_NODES + RPB1 - 1) / RPB1)   // 293
#define CHUNK1 4096                     // edges staged per block in P1
#define NCB    19                       // column blocks of 8192 (col>>13)
#define NCELL  (RPB1 * NCB)             // 9728 p2 LDS cells

// ---------------------------------------------------------------------------
// Threefry-2x32, 20 rounds (JAX-compatible; verified passing).
// ---------------------------------------------------------------------------
__host__ __device__ __forceinline__ void tf_block(unsigned k0, unsigned k1,
                                                  unsigned x0, unsigned x1,
                                                  unsigned& o0, unsigned& o1) {
    unsigned ks[3] = {k0, k1, k0 ^ k1 ^ 0x1BD11BDAu};
    unsigned X0 = x0 + ks[0];
    unsigned X1 = x1 + ks[1];
    const int R[2][4] = {{13, 15, 26, 6}, {17, 29, 16, 24}};
#pragma unroll
    for (int i = 0; i < 5; ++i) {
        const int* r = R[i & 1];
#pragma unroll
        for (int j = 0; j < 4; ++j) {
            X0 += X1;
            X1 = (X1 << r[j]) | (X1 >> (32 - r[j]));
            X1 ^= X0;
        }
        X0 += ks[(i + 1) % 3];
        X1 += ks[(i + 2) % 3] + (unsigned)(i + 1);
    }
    o0 = X0; o1 = X1;
}

__device__ __forceinline__ unsigned short f_to_bfu(float f) {
    __hip_bfloat16 b = __float2bfloat16(f);   // RNE
    return *(unsigned short*)&b;
}
__device__ __forceinline__ float bfu_to_f(unsigned short u) {
    return __uint_as_float((unsigned)u << 16);
}

// ---------------------------------------------------------------------------
// Bucket histogram, LDS-aggregated (<=293 global atomics per block).
// ---------------------------------------------------------------------------
#define BHIST_BLOCKS 2048
__global__ __launch_bounds__(256) void bhist_k(const int* __restrict__ rows,
                                               int* __restrict__ bb) {
    __shared__ int h[NB1];
    for (int i = threadIdx.x; i < NB1; i += 256) h[i] = 0;
    __syncthreads();
    const int stride = BHIST_BLOCKS * 256;
    for (int e = blockIdx.x * 256 + threadIdx.x; e < NNZ; e += stride)
        atomicAdd(&h[rows[e] >> 9], 1);
    __syncthreads();
    for (int i = threadIdx.x; i < NB1; i += 256)
        if (h[i]) atomicAdd(&bb[i], h[i]);
}

__global__ __launch_bounds__(512) void bscan_k(int* __restrict__ bb,
                                               int* __restrict__ bcur) {
    __shared__ int sh[512];
    int t = threadIdx.x;
    int v = (t < NB1) ? bb[t] : 0;
    sh[t] = v;
    __syncthreads();
    for (int off = 1; off < 512; off <<= 1) {
        int x = (t >= off) ? sh[t - off] : 0;
        __syncthreads();
        sh[t] += x;
        __syncthreads();
    }
    int ex = sh[t] - v;  // exclusive prefix
    if (t < NB1) { bb[t] = ex; bcur[t] = ex; }
    if (t == NB1 - 1) bb[NB1] = sh[t];   // sentinel = NNZ
}

// ---------------------------------------------------------------------------
// P1: LDS-staged coarse scatter (write-combined).
// ---------------------------------------------------------------------------
__global__ __launch_bounds__(256) void p1_k(const int* __restrict__ rows,
                                            const int* __restrict__ cols,
                                            const float* __restrict__ vals,
                                            int* __restrict__ bcur,
                                            int2* __restrict__ tmp) {
    __shared__ int2 stage[CHUNK1];               // 32 KB
    __shared__ unsigned short sb[CHUNK1];        // 8 KB: bucket id per slot
    __shared__ int hist[NB1], lbase[NB1], lcur[NB1], gbase[NB1];
    const int tid = threadIdx.x;
    const int c0 = blockIdx.x * CHUNK1;
    const int n = (c0 + CHUNK1 <= NNZ) ? CHUNK1 : (NNZ - c0);

    for (int b = tid; b < NB1; b += 256) hist[b] = 0;
    __syncthreads();

    int2 pay[CHUNK1 / 256];
    int  pb[CHUNK1 / 256];
#pragma unroll
    for (int k = 0; k < CHUNK1 / 256; ++k) {
        int i = tid + k * 256;
        if (i < n) {
            int e = c0 + i;
            int r = rows[e];
            int b = r >> 9;
            pay[k] = make_int2(cols[e] | ((r & 511) << 18),
                               __float_as_int(vals[e]));
            pb[k] = b;
            atomicAdd(&hist[b], 1);
        } else pb[k] = -1;
    }
    __syncthreads();

    if (tid == 0) {
        int run = 0;
        for (int b = 0; b < NB1; ++b) {
            lbase[b] = run;
            lcur[b] = run;
            run += hist[b];
        }
    }
    __syncthreads();
    for (int b = tid; b < NB1; b += 256)
        if (hist[b] > 0) gbase[b] = atomicAdd(&bcur[b], hist[b]);
    __syncthreads();

#pragma unroll
    for (int k = 0; k < CHUNK1 / 256; ++k) {
        if (pb[k] >= 0) {
            int pos = atomicAdd(&lcur[pb[k]], 1);
            stage[pos] = pay[k];
            sb[pos] = (unsigned short)pb[k];
        }
    }
    __syncthreads();

    for (int i = tid; i < n; i += 256) {
        int b = sb[i];
        tmp[gbase[b] + (i - lbase[b])] = stage[i];
    }
}

// ---------------------------------------------------------------------------
// P2: block per coarse bucket; (row, colblock)-sorted scatter + cur[] ends.
// ---------------------------------------------------------------------------
__global__ __launch_bounds__(256) void p2_k(const int* __restrict__ bb,
                                            const int2* __restrict__ tmp,
                                            int2* __restrict__ edges,
                                            int* __restrict__ cur) {
    __shared__ int lh[NCELL];     // 38.9 KB
    __shared__ int ps[256];
    int b = blockIdx.x;
    int tid = threadIdx.x;
    int base = bb[b];
    int cnt = bb[b + 1] - base;

    for (int i = tid; i < NCELL; i += 256) lh[i] = 0;
    __syncthreads();

    for (int i = tid; i < cnt; i += 256) {
        int x = tmp[base + i].x;
        int cell = ((x >> 18) & 511) * NCB + ((x & 0x3FFFF) >> 13);
        atomicAdd(&lh[cell], 1);
    }
    __syncthreads();

    const int PC = (NCELL + 255) / 256;   // 38
    int lo = tid * PC;
    int hi = lo + PC < NCELL ? lo + PC : NCELL;
    int s = 0;
    for (int i = lo; i < hi; ++i) s += lh[i];
    ps[tid] = s;
    __syncthreads();
    for (int off = 1; off < 256; off <<= 1) {
        int x = (tid >= off) ? ps[tid - off] : 0;
        __syncthreads();
        ps[tid] += x;
        __syncthreads();
    }
    int run = base + ps[tid] - s;
    for (int i = lo; i < hi; ++i) {
        int d = lh[i];
        lh[i] = run;
        run += d;
    }
    __syncthreads();

    for (int i = tid; i < cnt; i += 256) {
        int2 w = tmp[base + i];
        int cell = ((w.x >> 18) & 511) * NCB + ((w.x & 0x3FFFF) >> 13);
        int pos = atomicAdd(&lh[cell], 1);
        edges[pos] = make_int2(w.x & 0x3FFFF, w.y);
    }
    __syncthreads();

    int r0 = b * RPB1;
    for (int t = tid; t < RPB1; t += 256) {
        int r = r0 + t;
        if (r < N_NODES) cur[r] = lh[t * NCB + (NCB - 1)];
    }
}

// ---------------------------------------------------------------------------
// Pack layer-0 sources (pE spans ALL 150K rows: user slice then item slice —
// a single gather base for layer 0's E path; pIIT covers item rows only).
// ---------------------------------------------------------------------------
__global__ __launch_bounds__(256) void pack0_k(
    const float* __restrict__ user, const float* __restrict__ item,
    const float* __restrict__ image, const float* __restrict__ text,
    unsigned short* __restrict__ pE, unsigned* __restrict__ pIIT) {
    size_t idx = (size_t)blockIdx.x * 256 + threadIdx.x;
    if (idx < UMATF) {
        pE[idx] = f_to_bfu(user[idx]);
    }
    if (idx < IMATF) {
        pE[UMATF + idx] = f_to_bfu(item[idx]);
        pIIT[idx] = (unsigned)f_to_bfu(image[idx]) |
                    ((unsigned)f_to_bfu(text[idx]) << 16);
    }
}

// ---------------------------------------------------------------------------
// Shared epilogue: leaky-relu + dropout + optional write-back + l2norm + out.
// ---------------------------------------------------------------------------
__device__ __forceinline__ void epilogue(
    int row, int lane, float ae, float ai, float at,
    unsigned short* dE, unsigned* dIT, const float* w, float* out,
    unsigned ki0, unsigned ki1, unsigned kt0, unsigned kt1,
    int writeBack, bool first) {
    size_t idx = (size_t)row * EMB + lane;
    unsigned j = (unsigned)idx;

    float iv = ai >= 0.f ? ai : 0.01f * ai;      // leaky_relu
    float tv = at >= 0.f ? at : 0.01f * at;
    unsigned y0, y1;
    tf_block(ki0, ki1, 0u, j, y0, y1);
    iv = ((y0 ^ y1) >> 31) ? 0.f : iv * 2.f;     // dropout p=0.5, keep iff MSB==0
    tf_block(kt0, kt1, 0u, j, y0, y1);
    tv = ((y0 ^ y1) >> 31) ? 0.f : tv * 2.f;

    if (writeBack) {                              // next layer's SpMM inputs
        dE[idx]  = f_to_bfu(ae);
        dIT[idx] = (unsigned)f_to_bfu(iv) | ((unsigned)f_to_bfu(tv) << 16);
    }

    float si = iv * iv, st2 = tv * tv;
#pragma unroll
    for (int m = 1; m < 64; m <<= 1) {
        si  += __shfl_xor(si, m, 64);
        st2 += __shfl_xor(st2, m, 64);
    }
    float ni = iv / fmaxf(sqrtf(si), 1e-12f);
    float nt = tv / fmaxf(sqrtf(st2), 1e-12f);

    const float inv3 = 1.0f / 3.0f;
    float contrib = (row < USER_NUM) ? ae * inv3
                                     : (w[0] * ae + w[1] * ni + w[2] * nt) * inv3;
    if (first) out[idx] = contrib;
    else       out[idx] += contrib;
}

// ---------------------------------------------------------------------------
// Layer 0 SpMM: branchless 4-edge batching. E path gathers a single unified
// pE[c*64+lane] for all cols; I/T path clamps user cols to item row 0 (one
// L1-hot line, free) and selects xe for them after the load. Forces >=8
// loads in flight (round 12: branchy l0 = 8 VGPR = latency-bound 402 us).
// ---------------------------------------------------------------------------
__global__ __launch_bounds__(256) void spmm_l0(
    const int* __restrict__ cur, const int2* __restrict__ edges,
    const unsigned short* __restrict__ pE, const unsigned* __restrict__ pIIT,
    unsigned short* __restrict__ dE, unsigned* __restrict__ dIT,
    const float* __restrict__ w, float* __restrict__ out,
    unsigned ki0, unsigned ki1, unsigned kt0, unsigned kt1) {
    int row = (int)((blockIdx.x * 256u + threadIdx.x) >> 6);
    int lane = threadIdx.x & 63;
    if (row >= N_NODES) return;
    int beg = __builtin_amdgcn_readfirstlane((row == 0) ? 0 : cur[row - 1]);
    int end = __builtin_amdgcn_readfirstlane(cur[row]);
    float ae = 0.f, ai = 0.f, at = 0.f;

    int i = beg;
    for (; i + 4 <= end; i += 4) {
        int2 c0 = edges[i];
        int2 c1 = edges[i + 1];
        int2 c2 = edges[i + 2];
        int2 c3 = edges[i + 3];
        bool u0 = c0.x < USER_NUM;
        bool u1 = c1.x < USER_NUM;
        bool u2 = c2.x < USER_NUM;
        bool u3 = c3.x < USER_NUM;
        size_t aE0 = (size_t)c0.x * EMB + lane;
        size_t aE1 = (size_t)c1.x * EMB + lane;
        size_t aE2 = (size_t)c2.x * EMB + lane;
        size_t aE3 = (size_t)c3.x * EMB + lane;
        size_t aI0 = (size_t)(u0 ? 0 : c0.x - USER_NUM) * EMB + lane;
        size_t aI1 = (size_t)(u1 ? 0 : c1.x - USER_NUM) * EMB + lane;
        size_t aI2 = (size_t)(u2 ? 0 : c2.x - USER_NUM) * EMB + lane;
        size_t aI3 = (size_t)(u3 ? 0 : c3.x - USER_NUM) * EMB + lane;
        unsigned short e0 = pE[aE0];
        unsigned short e1 = pE[aE1];
        unsigned short e2 = pE[aE2];
        unsigned short e3 = pE[aE3];
        unsigned t0 = pIIT[aI0];
        unsigned t1 = pIIT[aI1];
        unsigned t2 = pIIT[aI2];
        unsigned t3 = pIIT[aI3];
        float v0 = __int_as_float(c0.y);
        float v1 = __int_as_float(c1.y);
        float v2 = __int_as_float(c2.y);
        float v3 = __int_as_float(c3.y);
        float xe0 = bfu_to_f(e0);
        float xe1 = bfu_to_f(e1);
        float xe2 = bfu_to_f(e2);
        float xe3 = bfu_to_f(e3);
        ae += v0 * xe0;
        ai += v0 * (u0 ? xe0 : __uint_as_float(t0 << 16));
        at += v0 * (u0 ? xe0 : __uint_as_float(t0 & 0xffff0000u));
        ae += v1 * xe1;
        ai += v1 * (u1 ? xe1 : __uint_as_float(t1 << 16));
        at += v1 * (u1 ? xe1 : __uint_as_float(t1 & 0xffff0000u));
        ae += v2 * xe2;
        ai += v2 * (u2 ? xe2 : __uint_as_float(t2 << 16));
        at += v2 * (u2 ? xe2 : __uint_as_float(t2 & 0xffff0000u));
        ae += v3 * xe3;
        ai += v3 * (u3 ? xe3 : __uint_as_float(t3 << 16));
        at += v3 * (u3 ? xe3 : __uint_as_float(t3 & 0xffff0000u));
    }
    for (; i < end; ++i) {
        int2 cv = edges[i];
        bool u = cv.x < USER_NUM;
        float v = __int_as_float(cv.y);
        float xe = bfu_to_f(pE[(size_t)cv.x * EMB + lane]);
        unsigned it = pIIT[(size_t)(u ? 0 : cv.x - USER_NUM) * EMB + lane];
        ae += v * xe;
        ai += v * (u ? xe : __uint_as_float(it << 16));
        at += v * (u ? xe : __uint_as_float(it & 0xffff0000u));
    }
    epilogue(row, lane, ae, ai, at, dE, dIT, w, out,
             ki0, ki1, kt0, kt1, 1, true);
}

// ---------------------------------------------------------------------------
// Layers 1-2 SpMM: manual 4-edge batching (restored l12 to ~335 us, r12).
// ---------------------------------------------------------------------------
__global__ __launch_bounds__(256) void spmm_l12(
    const int* __restrict__ cur, const int2* __restrict__ edges,
    const unsigned short* __restrict__ sE, const unsigned* __restrict__ sIT,
    unsigned short* __restrict__ dE, unsigned* __restrict__ dIT,
    const float* __restrict__ w, float* __restrict__ out,
    unsigned ki0, unsigned ki1, unsigned kt0, unsigned kt1, int writeBack) {
    int row = (int)((blockIdx.x * 256u + threadIdx.x) >> 6);
    int lane = threadIdx.x & 63;
    if (row >= N_NODES) return;
    int beg = __builtin_amdgcn_readfirstlane((row == 0) ? 0 : cur[row - 1]);
    int end = __builtin_amdgcn_readfirstlane(cur[row]);
    float ae = 0.f, ai = 0.f, at = 0.f;

    int i = beg;
    for (; i + 4 <= end; i += 4) {
        int2 c0 = edges[i];
        int2 c1 = edges[i + 1];
        int2 c2 = edges[i + 2];
        int2 c3 = edges[i + 3];
        size_t a0 = (size_t)c0.x * EMB + lane;
        size_t a1 = (size_t)c1.x * EMB + lane;
        size_t a2 = (size_t)c2.x * EMB + lane;
        size_t a3 = (size_t)c3.x * EMB + lane;
        unsigned short e0 = sE[a0];
        unsigned short e1 = sE[a1];
        unsigned short e2 = sE[a2];
        unsigned short e3 = sE[a3];
        unsigned t0 = sIT[a0];
        unsigned t1 = sIT[a1];
        unsigned t2 = sIT[a2];
        unsigned t3 = sIT[a3];
        float v0 = __int_as_float(c0.y);
        float v1 = __int_as_float(c1.y);
        float v2 = __int_as_float(c2.y);
        float v3 = __int_as_float(c3.y);
        ae += v0 * bfu_to_f(e0);
        ai += v0 * __uint_as_float(t0 << 16);
        at += v0 * __uint_as_float(t0 & 0xffff0000u);
        ae += v1 * bfu_to_f(e1);
        ai += v1 * __uint_as_float(t1 << 16);
        at += v1 * __uint_as_float(t1 & 0xffff0000u);
        ae += v2 * bfu_to_f(e2);
        ai += v2 * __uint_as_float(t2 << 16);
        at += v2 * __uint_as_float(t2 & 0xffff0000u);
        ae += v3 * bfu_to_f(e3);
        ai += v3 * __uint_as_float(t3 << 16);
        at += v3 * __uint_as_float(t3 & 0xffff0000u);
    }
    for (; i < end; ++i) {
        int2 cv = edges[i];
        size_t cc = (size_t)cv.x * EMB + lane;
        float v = __int_as_float(cv.y);
        unsigned short xe = sE[cc];
        unsigned it = sIT[cc];
        ae += v * bfu_to_f(xe);
        ai += v * __uint_as_float(it << 16);
        at += v * __uint_as_float(it & 0xffff0000u);
    }
    epilogue(row, lane, ae, ai, at, dE, dIT, w, out,
             ki0, ki1, kt0, kt1, writeBack, false);
}

// ---------------------------------------------------------------------------
extern "C" void kernel_launch(void* const* d_in, const int* in_sizes, int n_in,
                              void* d_out, int out_size, void* d_ws, size_t ws_size,
                              hipStream_t stream) {
    const float* user  = (const float*)d_in[0];
    const float* item  = (const float*)d_in[1];
    const float* image = (const float*)d_in[2];
    const float* text  = (const float*)d_in[3];
    const float* w     = (const float*)d_in[4];
    const float* vals  = (const float*)d_in[5];
    const int*   rows  = (const int*)d_in[6];
    const int*   cols  = (const int*)d_in[7];
    float* out = (float*)d_out;

    // workspace layout (~199 MB)
    int2* edges = (int2*)d_ws;                               // NNZ * 8B
    unsigned short* eA = (unsigned short*)(edges + NNZ);     // E ping (bf16)
    unsigned short* eB = eA + MATF;                          // E pong
    unsigned* itA = (unsigned*)(eB + MATF);                  // IT ping (2xbf16)
    unsigned* itB = itA + MATF;                              // IT pong
    unsigned short* pE = (unsigned short*)(itB + MATF);      // unified E (150K rows)
    unsigned* pIIT = (unsigned*)(pE + MATF);                 // item I|T slice
    int* cur  = (int*)(pIIT + IMATF);                        // N_NODES
    int* bb   = cur + N_NODES;                               // NB1 + 1
    int* bcur = bb + (NB1 + 2);                              // NB1
    // tmp bucket buffer aliased onto (eB, itA): dead after p2_k completes.
    int2* tmp = (int2*)eB;                                   // NNZ * 8B

    // ---- CSR build: bucket hist/scan + write-combined 2-pass sort ----
    hipMemsetAsync(bb, 0, (NB1 + 1) * sizeof(int), stream);
    bhist_k<<<BHIST_BLOCKS, 256, 0, stream>>>(rows, bb);
    bscan_k<<<1, 512, 0, stream>>>(bb, bcur);
    p1_k<<<(NNZ + CHUNK1 - 1) / CHUNK1, 256, 0, stream>>>(rows, cols, vals,
                                                          bcur, tmp);
    p2_k<<<NB1, 256, 0, stream>>>(bb, tmp, edges, cur);

    const int blocks = (int)((MATF + 255) / 256);  // 37500: one wave per row
    pack0_k<<<(int)((UMATF + 255) / 256), 256, 0, stream>>>(
        user, item, image, text, pE, pIIT);

    // layer keys
    unsigned a0[3], a1[3], b0[3], b1[3];
    for (int k = 0; k < 3; ++k) {
        unsigned f0, f1;
        tf_block(0u, 42u, 0u, (unsigned)k, f0, f1);
        tf_block(f0, f1, 0u, 0u, a0[k], a1[k]);
        tf_block(f0, f1, 0u, 1u, b0[k], b1[k]);
    }

    // layer 0: reads pE/pIIT, writes eA/itA
    spmm_l0<<<blocks, 256, 0, stream>>>(
        cur, edges, pE, pIIT, eA, itA, w, out, a0[0], a1[0], b0[0], b1[0]);
    // layer 1: reads eA/itA, writes eB/itB
    spmm_l12<<<blocks, 256, 0, stream>>>(
        cur, edges, eA, itA, eB, itB, w, out, a0[1], a1[1], b0[1], b1[1], 1);
    // layer 2: reads eB/itB, writes nothing
    spmm_l12<<<blocks, 256, 0, stream>>>(
        cur, edges, eB, itB, nullptr, nullptr, w, out, a0[2], a1[2], b0[2], b1[2], 0);
}

// Round 16
// 1098.794 us; speedup vs baseline: 1.2279x; 1.0674x over previous
//
#include <hip/hip_runtime.h>
#include <hip/hip_bf16.h>

#define USER_NUM 100000
#define N_NODES  150000
#define EMB      64
#define NNZ      6400000
#define MATF ((size_t)N_NODES * EMB)   // elems per matrix (9.6M)
#define UMATF ((size_t)USER_NUM * EMB) // user-slice elems (6.4M)
#define IMATF ((size_t)(N_NODES - USER_NUM) * EMB) // item-slice elems (3.2M)

#define RPB1   256                      // rows per bucket (row>>8)
#define NB1    ((N_NODES + RPB1 - 1) / RPB1)   // 586
#define BCAP   11776                    // bucket capacity (mean 10922, +8 sigma)
#define CHUNK1 4096                     // edges staged per block in P1

// ---------------------------------------------------------------------------
// Threefry-2x32, 20 rounds (JAX-compatible; verified passing).
// ---------------------------------------------------------------------------
__host__ __device__ __forceinline__ void tf_block(unsigned k0, unsigned k1,
                                                  unsigned x0, unsigned x1,
                                                  unsigned& o0, unsigned& o1) {
    unsigned ks[3] = {k0, k1, k0 ^ k1 ^ 0x1BD11BDAu};
    unsigned X0 = x0 + ks[0];
    unsigned X1 = x1 + ks[1];
    const int R[2][4] = {{13, 15, 26, 6}, {17, 29, 16, 24}};
#pragma unroll
    for (int i = 0; i < 5; ++i) {
        const int* r = R[i & 1];
#pragma unroll
        for (int j = 0; j < 4; ++j) {
            X0 += X1;
            X1 = (X1 << r[j]) | (X1 >> (32 - r[j]));
            X1 ^= X0;
        }
        X0 += ks[(i + 1) % 3];
        X1 += ks[(i + 2) % 3] + (unsigned)(i + 1);
    }
    o0 = X0; o1 = X1;
}

__device__ __forceinline__ unsigned short f_to_bfu(float f) {
    __hip_bfloat16 b = __float2bfloat16(f);   // RNE
    return *(unsigned short*)&b;
}
__device__ __forceinline__ float bfu_to_f(unsigned short u) {
    return __uint_as_float((unsigned)u << 16);
}

// ---------------------------------------------------------------------------
// Fixed-capacity bucket cursors: bcur[b] = b*BCAP (re-init every call).
// ---------------------------------------------------------------------------
__global__ __launch_bounds__(256) void binit_k(int* __restrict__ bcur) {
    int b = blockIdx.x * 256 + threadIdx.x;
    if (b < NB1) bcur[b] = b * BCAP;
}

// ---------------------------------------------------------------------------
// P1: LDS-staged coarse scatter into fixed-capacity buckets (write-combined).
// tmp payload: x = col | (row & 255) << 18, y = bits(val).
// ---------------------------------------------------------------------------
__global__ __launch_bounds__(256) void p1_k(const int* __restrict__ rows,
                                            const int* __restrict__ cols,
                                            const float* __restrict__ vals,
                                            int* __restrict__ bcur,
                                            int2* __restrict__ tmp) {
    __shared__ int2 stage[CHUNK1];               // 32 KB
    __shared__ unsigned short sb[CHUNK1];        // 8 KB: bucket id per slot
    __shared__ int hist[NB1], lbase[NB1], lcur[NB1], gbase[NB1];
    const int tid = threadIdx.x;
    const int c0 = blockIdx.x * CHUNK1;
    const int n = (c0 + CHUNK1 <= NNZ) ? CHUNK1 : (NNZ - c0);

    for (int b = tid; b < NB1; b += 256) hist[b] = 0;
    __syncthreads();

    int2 pay[CHUNK1 / 256];
    int  pb[CHUNK1 / 256];
#pragma unroll
    for (int k = 0; k < CHUNK1 / 256; ++k) {
        int i = tid + k * 256;
        if (i < n) {
            int e = c0 + i;
            int r = rows[e];
            int b = r >> 8;
            pay[k] = make_int2(cols[e] | ((r & 255) << 18),
                               __float_as_int(vals[e]));
            pb[k] = b;
            atomicAdd(&hist[b], 1);
        } else pb[k] = -1;
    }
    __syncthreads();

    if (tid == 0) {
        int run = 0;
        for (int b = 0; b < NB1; ++b) {
            lbase[b] = run;
            lcur[b] = run;
            run += hist[b];
        }
    }
    __syncthreads();
    // global space reservation: one atomic per non-empty bucket per chunk
    for (int b = tid; b < NB1; b += 256)
        if (hist[b] > 0) gbase[b] = atomicAdd(&bcur[b], hist[b]);
    __syncthreads();

#pragma unroll
    for (int k = 0; k < CHUNK1 / 256; ++k) {
        if (pb[k] >= 0) {
            int pos = atomicAdd(&lcur[pb[k]], 1);
            stage[pos] = pay[k];
            sb[pos] = (unsigned short)pb[k];
        }
    }
    __syncthreads();

    // flush: consecutive i within a bucket -> consecutive global addresses
    for (int i = tid; i < n; i += 256) {
        int b = sb[i];
        tmp[gbase[b] + (i - lbase[b])] = stage[i];
    }
}

// ---------------------------------------------------------------------------
// P2: one block per bucket. 256-cell row hist in LDS -> block scan ->
// row-sorted scatter into the bucket's fixed slice of edges[]. Emits exact
// per-row rbeg/rend (fixed-capacity layout has inter-bucket gaps, so both
// bounds are explicit).
// ---------------------------------------------------------------------------
__global__ __launch_bounds__(256) void p2_k(const int* __restrict__ bcur,
                                            const int2* __restrict__ tmp,
                                            int2* __restrict__ edges,
                                            int* __restrict__ rbeg,
                                            int* __restrict__ rend) {
    __shared__ int lh[RPB1];      // 1 KB: per-row cursor
    __shared__ int ps[256];
    int b = blockIdx.x;
    int tid = threadIdx.x;
    int base = b * BCAP;
    int cnt = bcur[b] - base;
    int r0 = b * RPB1;
    int nr = (r0 + RPB1 <= N_NODES) ? RPB1 : (N_NODES - r0);

    lh[tid] = 0;
    __syncthreads();

    for (int i = tid; i < cnt; i += 256)
        atomicAdd(&lh[(tmp[base + i].x >> 18) & 255], 1);
    __syncthreads();

    // exclusive block scan: lh[t] -> base + prefix
    int s = lh[tid];
    ps[tid] = s;
    __syncthreads();
    for (int off = 1; off < 256; off <<= 1) {
        int x = (tid >= off) ? ps[tid - off] : 0;
        __syncthreads();
        ps[tid] += x;
        __syncthreads();
    }
    lh[tid] = base + ps[tid] - s;
    __syncthreads();

    if (tid < nr) rbeg[r0 + tid] = lh[tid];   // row start (pre-scatter)
    __syncthreads();

    for (int i = tid; i < cnt; i += 256) {
        int2 w = tmp[base + i];
        int pos = atomicAdd(&lh[(w.x >> 18) & 255], 1);
        edges[pos] = make_int2(w.x & 0x3FFFF, w.y);
    }
    __syncthreads();

    if (tid < nr) rend[r0 + tid] = lh[tid];   // cursor == row end
}

// ---------------------------------------------------------------------------
// Pack layer-0 sources (pE spans ALL 150K rows: user slice then item slice —
// a single gather base for layer 0's E path; pIIT covers item rows only).
// ---------------------------------------------------------------------------
__global__ __launch_bounds__(256) void pack0_k(
    const float* __restrict__ user, const float* __restrict__ item,
    const float* __restrict__ image, const float* __restrict__ text,
    unsigned short* __restrict__ pE, unsigned* __restrict__ pIIT) {
    size_t idx = (size_t)blockIdx.x * 256 + threadIdx.x;
    if (idx < UMATF) {
        pE[idx] = f_to_bfu(user[idx]);
    }
    if (idx < IMATF) {
        pE[UMATF + idx] = f_to_bfu(item[idx]);
        pIIT[idx] = (unsigned)f_to_bfu(image[idx]) |
                    ((unsigned)f_to_bfu(text[idx]) << 16);
    }
}

// ---------------------------------------------------------------------------
// Shared epilogue: leaky-relu + dropout + optional write-back + l2norm + out.
// ---------------------------------------------------------------------------
__device__ __forceinline__ void epilogue(
    int row, int lane, float ae, float ai, float at,
    unsigned short* dE, unsigned* dIT, const float* w, float* out,
    unsigned ki0, unsigned ki1, unsigned kt0, unsigned kt1,
    int writeBack, bool first) {
    size_t idx = (size_t)row * EMB + lane;
    unsigned j = (unsigned)idx;

    float iv = ai >= 0.f ? ai : 0.01f * ai;      // leaky_relu
    float tv = at >= 0.f ? at : 0.01f * at;
    unsigned y0, y1;
    tf_block(ki0, ki1, 0u, j, y0, y1);
    iv = ((y0 ^ y1) >> 31) ? 0.f : iv * 2.f;     // dropout p=0.5, keep iff MSB==0
    tf_block(kt0, kt1, 0u, j, y0, y1);
    tv = ((y0 ^ y1) >> 31) ? 0.f : tv * 2.f;

    if (writeBack) {                              // next layer's SpMM inputs
        dE[idx]  = f_to_bfu(ae);
        dIT[idx] = (unsigned)f_to_bfu(iv) | ((unsigned)f_to_bfu(tv) << 16);
    }

    float si = iv * iv, st2 = tv * tv;
#pragma unroll
    for (int m = 1; m < 64; m <<= 1) {
        si  += __shfl_xor(si, m, 64);
        st2 += __shfl_xor(st2, m, 64);
    }
    float ni = iv / fmaxf(sqrtf(si), 1e-12f);
    float nt = tv / fmaxf(sqrtf(st2), 1e-12f);

    const float inv3 = 1.0f / 3.0f;
    float contrib = (row < USER_NUM) ? ae * inv3
                                     : (w[0] * ae + w[1] * ni + w[2] * nt) * inv3;
    if (first) out[idx] = contrib;
    else       out[idx] += contrib;
}

// ---------------------------------------------------------------------------
// Layer 0 SpMM: branchless 4-edge batching, unified pE base, clamped pIIT
// index for user cols (verified r14: l0 left the top-5).
// ---------------------------------------------------------------------------
__global__ __launch_bounds__(256) void spmm_l0(
    const int* __restrict__ rbeg, const int* __restrict__ rend,
    const int2* __restrict__ edges,
    const unsigned short* __restrict__ pE, const unsigned* __restrict__ pIIT,
    unsigned short* __restrict__ dE, unsigned* __restrict__ dIT,
    const float* __restrict__ w, float* __restrict__ out,
    unsigned ki0, unsigned ki1, unsigned kt0, unsigned kt1) {
    int row = (int)((blockIdx.x * 256u + threadIdx.x) >> 6);
    int lane = threadIdx.x & 63;
    if (row >= N_NODES) return;
    int beg = __builtin_amdgcn_readfirstlane(rbeg[row]);
    int end = __builtin_amdgcn_readfirstlane(rend[row]);
    float ae = 0.f, ai = 0.f, at = 0.f;

    int i = beg;
    for (; i + 4 <= end; i += 4) {
        int2 c0 = edges[i];
        int2 c1 = edges[i + 1];
        int2 c2 = edges[i + 2];
        int2 c3 = edges[i + 3];
        bool u0 = c0.x < USER_NUM;
        bool u1 = c1.x < USER_NUM;
        bool u2 = c2.x < USER_NUM;
        bool u3 = c3.x < USER_NUM;
        size_t aE0 = (size_t)c0.x * EMB + lane;
        size_t aE1 = (size_t)c1.x * EMB + lane;
        size_t aE2 = (size_t)c2.x * EMB + lane;
        size_t aE3 = (size_t)c3.x * EMB + lane;
        size_t aI0 = (size_t)(u0 ? 0 : c0.x - USER_NUM) * EMB + lane;
        size_t aI1 = (size_t)(u1 ? 0 : c1.x - USER_NUM) * EMB + lane;
        size_t aI2 = (size_t)(u2 ? 0 : c2.x - USER_NUM) * EMB + lane;
        size_t aI3 = (size_t)(u3 ? 0 : c3.x - USER_NUM) * EMB + lane;
        unsigned short e0 = pE[aE0];
        unsigned short e1 = pE[aE1];
        unsigned short e2 = pE[aE2];
        unsigned short e3 = pE[aE3];
        unsigned t0 = pIIT[aI0];
        unsigned t1 = pIIT[aI1];
        unsigned t2 = pIIT[aI2];
        unsigned t3 = pIIT[aI3];
        float v0 = __int_as_float(c0.y);
        float v1 = __int_as_float(c1.y);
        float v2 = __int_as_float(c2.y);
        float v3 = __int_as_float(c3.y);
        float xe0 = bfu_to_f(e0);
        float xe1 = bfu_to_f(e1);
        float xe2 = bfu_to_f(e2);
        float xe3 = bfu_to_f(e3);
        ae += v0 * xe0;
        ai += v0 * (u0 ? xe0 : __uint_as_float(t0 << 16));
        at += v0 * (u0 ? xe0 : __uint_as_float(t0 & 0xffff0000u));
        ae += v1 * xe1;
        ai += v1 * (u1 ? xe1 : __uint_as_float(t1 << 16));
        at += v1 * (u1 ? xe1 : __uint_as_float(t1 & 0xffff0000u));
        ae += v2 * xe2;
        ai += v2 * (u2 ? xe2 : __uint_as_float(t2 << 16));
        at += v2 * (u2 ? xe2 : __uint_as_float(t2 & 0xffff0000u));
        ae += v3 * xe3;
        ai += v3 * (u3 ? xe3 : __uint_as_float(t3 << 16));
        at += v3 * (u3 ? xe3 : __uint_as_float(t3 & 0xffff0000u));
    }
    for (; i < end; ++i) {
        int2 cv = edges[i];
        bool u = cv.x < USER_NUM;
        float v = __int_as_float(cv.y);
        float xe = bfu_to_f(pE[(size_t)cv.x * EMB + lane]);
        unsigned it = pIIT[(size_t)(u ? 0 : cv.x - USER_NUM) * EMB + lane];
        ae += v * xe;
        ai += v * (u ? xe : __uint_as_float(it << 16));
        at += v * (u ? xe : __uint_as_float(it & 0xffff0000u));
    }
    epilogue(row, lane, ae, ai, at, dE, dIT, w, out,
             ki0, ki1, kt0, kt1, 1, true);
}

// ---------------------------------------------------------------------------
// Layers 1-2 SpMM: manual 4-edge batching (at the random-gather service
// ceiling: 335 us / 1.19e6 KB FETCH, invariant across r7/r9/r14 variants).
// ---------------------------------------------------------------------------
__global__ __launch_bounds__(256) void spmm_l12(
    const int* __restrict__ rbeg, const int* __restrict__ rend,
    const int2* __restrict__ edges,
    const unsigned short* __restrict__ sE, const unsigned* __restrict__ sIT,
    unsigned short* __restrict__ dE, unsigned* __restrict__ dIT,
    const float* __restrict__ w, float* __restrict__ out,
    unsigned ki0, unsigned ki1, unsigned kt0, unsigned kt1, int writeBack) {
    int row = (int)((blockIdx.x * 256u + threadIdx.x) >> 6);
    int lane = threadIdx.x & 63;
    if (row >= N_NODES) return;
    int beg = __builtin_amdgcn_readfirstlane(rbeg[row]);
    int end = __builtin_amdgcn_readfirstlane(rend[row]);
    float ae = 0.f, ai = 0.f, at = 0.f;

    int i = beg;
    for (; i + 4 <= end; i += 4) {
        int2 c0 = edges[i];
        int2 c1 = edges[i + 1];
        int2 c2 = edges[i + 2];
        int2 c3 = edges[i + 3];
        size_t a0 = (size_t)c0.x * EMB + lane;
        size_t a1 = (size_t)c1.x * EMB + lane;
        size_t a2 = (size_t)c2.x * EMB + lane;
        size_t a3 = (size_t)c3.x * EMB + lane;
        unsigned short e0 = sE[a0];
        unsigned short e1 = sE[a1];
        unsigned short e2 = sE[a2];
        unsigned short e3 = sE[a3];
        unsigned t0 = sIT[a0];
        unsigned t1 = sIT[a1];
        unsigned t2 = sIT[a2];
        unsigned t3 = sIT[a3];
        float v0 = __int_as_float(c0.y);
        float v1 = __int_as_float(c1.y);
        float v2 = __int_as_float(c2.y);
        float v3 = __int_as_float(c3.y);
        ae += v0 * bfu_to_f(e0);
        ai += v0 * __uint_as_float(t0 << 16);
        at += v0 * __uint_as_float(t0 & 0xffff0000u);
        ae += v1 * bfu_to_f(e1);
        ai += v1 * __uint_as_float(t1 << 16);
        at += v1 * __uint_as_float(t1 & 0xffff0000u);
        ae += v2 * bfu_to_f(e2);
        ai += v2 * __uint_as_float(t2 << 16);
        at += v2 * __uint_as_float(t2 & 0xffff0000u);
        ae += v3 * bfu_to_f(e3);
        ai += v3 * __uint_as_float(t3 << 16);
        at += v3 * __uint_as_float(t3 & 0xffff0000u);
    }
    for (; i < end; ++i) {
        int2 cv = edges[i];
        size_t cc = (size_t)cv.x * EMB + lane;
        float v = __int_as_float(cv.y);
        unsigned short xe = sE[cc];
        unsigned it = sIT[cc];
        ae += v * bfu_to_f(xe);
        ai += v * __uint_as_float(it << 16);
        at += v * __uint_as_float(it & 0xffff0000u);
    }
    epilogue(row, lane, ae, ai, at, dE, dIT, w, out,
             ki0, ki1, kt0, kt1, writeBack, false);
}

// ---------------------------------------------------------------------------
extern "C" void kernel_launch(void* const* d_in, const int* in_sizes, int n_in,
                              void* d_out, int out_size, void* d_ws, size_t ws_size,
                              hipStream_t stream) {
    const float* user  = (const float*)d_in[0];
    const float* item  = (const float*)d_in[1];
    const float* image = (const float*)d_in[2];
    const float* text  = (const float*)d_in[3];
    const float* w     = (const float*)d_in[4];
    const float* vals  = (const float*)d_in[5];
    const int*   rows  = (const int*)d_in[6];
    const int*   cols  = (const int*)d_in[7];
    float* out = (float*)d_out;

    // workspace layout (~204 MB; round-1 proved >=230.4 MB available)
    const size_t EDGE_SLOTS = (size_t)NB1 * BCAP;            // 6.9M slots
    int2* edges = (int2*)d_ws;                               // 55.2 MB (sparse)
    unsigned short* eA = (unsigned short*)(edges + EDGE_SLOTS); // E ping
    unsigned short* eB = eA + MATF;                          // E pong
    unsigned* itA = (unsigned*)(eB + MATF);                  // IT ping (2xbf16)
    unsigned* itB = itA + MATF;                              // IT pong
    unsigned short* pE = (unsigned short*)(itB + MATF);      // unified E (150K rows)
    unsigned* pIIT = (unsigned*)(pE + MATF);                 // item I|T slice
    int* rbeg = (int*)(pIIT + IMATF);                        // N_NODES
    int* rend = rbeg + N_NODES;                              // N_NODES
    int* bcur = rend + N_NODES;                              // NB1
    // tmp bucket buffer aliased onto (eB, itA): 55.2 <= 57.6 MB; dead after
    // p2_k, first overwritten by spmm_l1 (stream-ordered later).
    int2* tmp = (int2*)eB;

    // ---- CSR build: fixed-capacity buckets, write-combined 2-pass sort ----
    binit_k<<<(NB1 + 255) / 256, 256, 0, stream>>>(bcur);
    p1_k<<<(NNZ + CHUNK1 - 1) / CHUNK1, 256, 0, stream>>>(rows, cols, vals,
                                                          bcur, tmp);
    p2_k<<<NB1, 256, 0, stream>>>(bcur, tmp, edges, rbeg, rend);

    const int blocks = (int)((MATF + 255) / 256);  // 37500: one wave per row
    pack0_k<<<(int)((UMATF + 255) / 256), 256, 0, stream>>>(
        user, item, image, text, pE, pIIT);

    // layer keys
    unsigned a0[3], a1[3], b0[3], b1[3];
    for (int k = 0; k < 3; ++k) {
        unsigned f0, f1;
        tf_block(0u, 42u, 0u, (unsigned)k, f0, f1);
        tf_block(f0, f1, 0u, 0u, a0[k], a1[k]);
        tf_block(f0, f1, 0u, 1u, b0[k], b1[k]);
    }

    // layer 0: reads pE/pIIT, writes eA/itA
    spmm_l0<<<blocks, 256, 0, stream>>>(
        rbeg, rend, edges, pE, pIIT, eA, itA, w, out,
        a0[0], a1[0], b0[0], b1[0]);
    // layer 1: reads eA/itA, writes eB/itB
    spmm_l12<<<blocks, 256, 0, stream>>>(
        rbeg, rend, edges, eA, itA, eB, itB, w, out,
        a0[1], a1[1], b0[1], b1[1], 1);
    // layer 2: reads eB/itB, writes nothing
    spmm_l12<<<blocks, 256, 0, stream>>>(
        rbeg, rend, edges, eB, itB, nullptr, nullptr, w, out,
        a0[2], a1[2], b0[2], b1[2], 0);
}